// Round 8
// baseline (2749.804 us; speedup 1.0000x reference)
//
#include <hip/hip_runtime.h>
#include <hip/hip_bf16.h>

typedef __attribute__((ext_vector_type(8))) short short8;
typedef __attribute__((ext_vector_type(4))) float f32x4;
typedef unsigned long long u64;
typedef unsigned int u32;

#define SQLEN 256
#define BATCH 128
#define HID   1024
#define NCLS  1000

static __device__ __forceinline__ float sigm(float x){ return 1.0f/(1.0f+__expf(-x)); }
static __device__ __forceinline__ float tanhx(float x){ return 2.0f/(1.0f+__expf(-2.0f*x)) - 1.0f; }
static __device__ __forceinline__ short bf16b(float x){
  __hip_bfloat16 h = __float2bfloat16(x);
  return __builtin_bit_cast(short, h);
}
static __device__ __forceinline__ float bf2f(short s){
  return __bfloat162float(__builtin_bit_cast(__hip_bfloat16, s));
}

// ---- prep: cast x [B][S][I] fp32 -> xbf [(s*128+b)][I] bf16 (permuted) ----
__global__ void cast_x_kernel(const float* __restrict__ x, short* __restrict__ xbf){
  int r = blockIdx.x;            // r = s*128 + b
  int s = r >> 7, b = r & 127;
  const float* src = x + ((size_t)b*SQLEN + s)*HID;
  short* dst = xbf + (size_t)r*HID;
  int k = threadIdx.x*4;
  float4 v = *(const float4*)(src + k);
  short4 o; o.x=bf16b(v.x); o.y=bf16b(v.y); o.z=bf16b(v.z); o.w=bf16b(v.w);
  *(short4*)(dst + k) = o;
}

__global__ void cast_w_kernel(const float* __restrict__ src, short* __restrict__ dst){
  int i = (blockIdx.x*256 + threadIdx.x)*4;
  float4 v = *(const float4*)(src + i);
  short4 o; o.x=bf16b(v.x); o.y=bf16b(v.y); o.z=bf16b(v.z); o.w=bf16b(v.w);
  *(short4*)(dst + i) = o;
}

__global__ void bias_kernel(const float* __restrict__ a, const float* __restrict__ b,
                            float* __restrict__ o){
  int i = blockIdx.x*256 + threadIdx.x;
  o[i] = a[i] + b[i];
}

// ---- fused xw-GEMM + persistent LSTM recurrence, v3 (barrier-free chunk) ----
// R6/R7 post-mortem: the in-loop gemm chunk cost ~5us/step REGARDLESS of
// placement, because each gemm_kk was issue->__syncthreads(vmcnt0)->use:
// full HBM latency exposed + 2 extra block barriers per kk. v3 removes ALL
// chunk-owned barriers: staging is double-buffered (Ast/Bst[2]) and each
// phase issues kk q+1 / computes kk q, with the RECURRENCE's two existing
// __syncthreads per step providing the drain+visibility (syncthreads drains
// the issuing wave's vmcnt). Phase0 (top of step, inside spin slack):
// stage 2t+1 / compute 2t. Region2 (after reduce barrier): stage 2t+2 /
// compute 2t+1 (+ epilogue stores on kk31; gcnt++ after tail barrier).
// Buffer audit: phase p reads buf[p&1], DMA-writes buf[(p+1)&1]; write
// target's previous readers finished before the intervening barrier; every
// compute's data was issued one barrier earlier. Schedule (rounds 0,1 in
// prologue; round k>=2 over steps 16(k-2)..+15, ready 16 steps before use),
// gating and the entire R1 recurrence are unchanged from R7 (passed).
// LDS 64KB -> still 2 blocks/CU.
__global__ __launch_bounds__(256,2) void lstm_fused_kernel(
    const short* __restrict__ xbf, const short* __restrict__ wxh,
    const float* __restrict__ bias, const short* __restrict__ whh,
    short* __restrict__ xw, short* __restrict__ h_all,
    u32* __restrict__ flags, u32* __restrict__ gcnt)
{
  __shared__ f32x4 part[2][4][4][64];            // 32 KB reduce buffer
  __shared__ __align__(16) short Ast[2][4096];   // 2 x 8 KB gemm A stage
  __shared__ __align__(16) short Bst[2][4096];   // 2 x 8 KB gemm B stage

  const int tid  = threadIdx.x;
  const int lane = tid & 63;
  const int wave = tid >> 6;            // recurrence K-slice 0..3 (256 each)
  const int l15  = lane & 15;
  const int quad = lane >> 4;
  const int bid  = (int)blockIdx.x;
  const int bg = bid & 7;               // batch group
  const int jg = bid >> 3;              // 0..63
  const int b0 = bg*16;
  const int j0 = jg*16;
  const int ks0 = wave*256;
  const int wm = (wave>>1)*64, wn = (wave&1)*64; // gemm output quadrant
  const int c0 = wave*64 + lane;        // gemm staging slot, rep 0
  const int c1 = c0 + 256;              // rep 1
  const int gbn = bid & 31;             // gemm N-tile of this block
  const size_t gn0 = (size_t)gbn*128;
  const int gbmi = bid >> 5;            // M-tile index within a round

  __builtin_amdgcn_fence(__ATOMIC_ACQUIRE, "agent");  // once: clear stale L2

  f32x4 gacc[4][4];
  auto gzero = [&]{
    #pragma unroll
    for (int m=0;m<4;++m)
      #pragma unroll
      for (int n=0;n<4;++n) gacc[m][n] = (f32x4)0.0f;
  };
  // issue the 4 staging DMAs for one K-step into buffer `buf` (no waits)
  auto stage = [&](int buf, size_t gr0, int kk){
    const int k0 = kk*32;
    __builtin_amdgcn_global_load_lds(
        (const void*)(xbf + (gr0 + (c0>>2))*HID + k0 + (c0&3)*8),
        (void*)((char*)&Ast[buf][0] + wave*1024), 16, 0, 0);
    __builtin_amdgcn_global_load_lds(
        (const void*)(xbf + (gr0 + (c1>>2))*HID + k0 + (c1&3)*8),
        (void*)((char*)&Ast[buf][0] + 4096 + wave*1024), 16, 0, 0);
    __builtin_amdgcn_global_load_lds(
        (const void*)(wxh + (gn0 + (c0>>2))*HID + k0 + (c0&3)*8),
        (void*)((char*)&Bst[buf][0] + wave*1024), 16, 0, 0);
    __builtin_amdgcn_global_load_lds(
        (const void*)(wxh + (gn0 + (c1>>2))*HID + k0 + (c1&3)*8),
        (void*)((char*)&Bst[buf][0] + 4096 + wave*1024), 16, 0, 0);
  };
  // consume buffer `buf` (staged >=1 __syncthreads ago): ds_read + 16 MFMA
  auto gcompute = [&](int buf){
    short8 af[4], bv[4];
    #pragma unroll
    for (int m=0;m<4;++m) af[m] = *(const short8*)(&Ast[buf][0] + (wm + m*16 + l15)*32 + quad*8);
    #pragma unroll
    for (int n=0;n<4;++n) bv[n] = *(const short8*)(&Bst[buf][0] + (wn + n*16 + l15)*32 + quad*8);
    #pragma unroll
    for (int m=0;m<4;++m)
      #pragma unroll
      for (int n=0;n<4;++n)
        gacc[m][n] = __builtin_amdgcn_mfma_f32_16x16x32_bf16(af[m], bv[n], gacc[m][n], 0,0,0);
  };
  // tile output: bias + pack -> agent-scope 8B stores (NO barrier, NO gcnt)
  auto gstore = [&](int gbm){
    #pragma unroll
    for (int n=0;n<4;++n){
      int s = gbn*128 + wn + n*16;
      float bs = bias[s + l15];
      int g = s >> 10, jgi = (s & 1023) >> 4;
      #pragma unroll
      for (int m=0;m<4;++m){
        #pragma unroll
        for (int rg=0; rg<4; ++rg){
          u32 w0 = (u32)(unsigned short)bf16b(gacc[m][n][rg] + bs);
          u32 w1 = __shfl_down(w0, 1);
          u32 w2 = __shfl_down(w0, 2);
          u32 w3 = __shfl_down(w0, 3);
          if ((l15 & 3) == 0){
            u64 pk = (u64)w0 | ((u64)w1<<16) | ((u64)w2<<32) | ((u64)w3<<48);
            int rowin = wm + m*16 + quad*4 + rg;   // batch b 0..127
            __hip_atomic_store(
              (u64*)(xw + (((size_t)gbm*64 + jgi)*128 + rowin)*64 + g*16 + l15),
              pk, __ATOMIC_RELAXED, __HIP_MEMORY_SCOPE_AGENT);
          }
        }
      }
    }
  };

  // ---- gemm prologue: rounds 0,1 (s=0..31), proven 2-barrier form ----
  #pragma unroll 1
  for (int rr = 0; rr < 2; ++rr){
    gzero();
    const int gbm = rr*16 + gbmi;
    const size_t gr0 = (size_t)gbm*128;
    #pragma unroll 1
    for (int kk = 0; kk < 32; ++kk){
      __syncthreads();               // prior buf0 reads done
      stage(0, gr0, kk);
      __syncthreads();               // DMA drained
      gcompute(0);
    }
    gstore(gbm);
    __syncthreads();                 // stores drained (vmcnt0 at barrier)
    if (tid == 0)
      __hip_atomic_fetch_add(gcnt + gbm, 1u, __ATOMIC_RELAXED,
                             __HIP_MEMORY_SCOPE_AGENT);
  }
  gzero();

  // Whh slice, MFMA B-fragment layout (no pinning -- see rounds 2/3)
  short8 Bf[4][8];
  #pragma unroll
  for (int g=0; g<4; ++g)
    #pragma unroll
    for (int kit=0; kit<8; ++kit)
      Bf[g][kit] = *(const short8*)(whh + (size_t)(g*1024 + j0 + l15)*HID
                                    + ks0 + kit*32 + quad*8);

  // pipeline preload: q=0 (round 2, kk 0) into buf0
  stage(0, (size_t)(2*16 + gbmi)*128, 0);
  __syncthreads();                   // q=0 drained; visible to all waves

  u32* fgrp = flags + bg*64;         // one h-flag per producer block

  // elementwise cell mapping: cell = tid (r 0..15 x jj 0..15)
  const int r  = tid >> 4;
  const int jj = tid & 15;
  const int ln = (r>>2)*16 + jj;     // frag lane of cell
  const int rg = r & 3;              // frag reg of cell
  float cc = 0.0f;                   // cell state in register

  // gated prefetch of xw for t=0
  short xwc[4];
  {
    while (__hip_atomic_load(gcnt + 0, __ATOMIC_RELAXED,
                             __HIP_MEMORY_SCOPE_AGENT) < 32u)
      __builtin_amdgcn_s_sleep(1);
    asm volatile("" ::: "memory");
    const short* xb = xw + (((size_t)0*64 + jg)*128 + b0 + r)*64 + jj;
    #pragma unroll
    for (int g=0; g<4; ++g) xwc[g] = xb[g*16];
  }

  for (int t = 0; t < SQLEN; ++t){
    const short* hin  = h_all + (size_t)t*131072;
    short*       hout = h_all + (size_t)(t+1)*131072;

    // ---- phase0 gemm (off-chain, inside spin slack): stage q=2t+1,
    // compute q=2t (staged last phase, drained by tail barrier) ----
    {
      const int q1 = 2*t + 1;
      if (q1 < 448) stage(1, (size_t)((2 + q1/32)*16 + gbmi)*128, q1 & 31);
      const int q0 = 2*t;
      if (q0 < 448) gcompute(0);
    }

    // gated early prefetch of next step's xw (ready >=16 steps early)
    short xwn[4];
    if (t < SQLEN-1){
      while (__hip_atomic_load(gcnt + (t+1), __ATOMIC_RELAXED,
                               __HIP_MEMORY_SCOPE_AGENT) < 32u)
        __builtin_amdgcn_s_sleep(1);
      asm volatile("" ::: "memory");
      const short* xb = xw + (((size_t)(t+1)*64 + jg)*128 + b0 + r)*64 + jj;
      #pragma unroll
      for (int g=0; g<4; ++g) xwn[g] = xb[g*16];
    }

    // per-wave spin: the 16 producer blocks of THIS wave's K-slice
    if (t){
      u32* fp = fgrp + wave*16 + l15;
      while (__hip_atomic_load(fp, __ATOMIC_RELAXED,
                               __HIP_MEMORY_SCOPE_AGENT) < (u32)t)
        __builtin_amdgcn_s_sleep(1);
      asm volatile("" ::: "memory");   // no hoist of h loads above the spin
    }

    // h fragments: plain cached coalesced 16B loads (fresh addresses)
    short8 Af[8];
    #pragma unroll
    for (int kit=0; kit<8; ++kit)
      Af[kit] = *(const short8*)(hin + (size_t)(b0 + l15)*HID
                                 + ks0 + kit*32 + quad*8);

    f32x4 acc[4];
    #pragma unroll
    for (int g=0; g<4; ++g) acc[g] = (f32x4)0.0f;
    #pragma unroll
    for (int kit=0; kit<8; ++kit)
      #pragma unroll
      for (int g=0; g<4; ++g)
        acc[g] = __builtin_amdgcn_mfma_f32_16x16x32_bf16(Af[kit], Bf[g][kit], acc[g],0,0,0);

    // single-pass cross-wave reduce, all 4 gates, double-buffered
    const int pb = t & 1;
    #pragma unroll
    for (int g=0; g<4; ++g) part[pb][wave][g][lane] = acc[g];
    __syncthreads();                  // (also drains phase0's stage DMA)

    // ---- region2 gemm, part 1: stage q=2t+2 early (latency overlaps
    // the reduce/gates below; drained by the tail barrier) ----
    {
      const int q2 = 2*t + 2;
      if (q2 < 448) stage(0, (size_t)((2 + q2/32)*16 + gbmi)*128, q2 & 31);
    }

    float gv[4];
    #pragma unroll
    for (int g=0; g<4; ++g){
      float s = bf2f(xwc[g]);
      #pragma unroll
      for (int w=0; w<4; ++w)
        s += ((const float*)&part[pb][w][g][ln])[rg];
      gv[g] = s;
    }

    float it = sigm(gv[0]), ft = sigm(gv[1]), ch = tanhx(gv[2]), ot = sigm(gv[3]);
    cc = cc*ft + it*ch;
    float hv = ot * tanhx(cc);

    // pack 4 adjacent cells -> one 8B write-through store
    u32 w0 = (u32)(unsigned short)bf16b(hv);
    u32 w1 = __shfl_down(w0, 1);
    u32 w2 = __shfl_down(w0, 2);
    u32 w3 = __shfl_down(w0, 3);
    if (!(tid & 3)){
      u64 hp = (u64)w0 | ((u64)w1<<16) | ((u64)w2<<32) | ((u64)w3<<48);
      __hip_atomic_store((u64*)(hout + (size_t)(b0 + r)*HID + j0 + jj), hp,
                         __ATOMIC_RELAXED, __HIP_MEMORY_SCOPE_AGENT);
    }
    xwc[0]=xwn[0]; xwc[1]=xwn[1]; xwc[2]=xwn[2]; xwc[3]=xwn[3];

    // ---- region2 gemm, part 2: compute q=2t+1 (staged at phase0,
    // drained by the reduce barrier); tile output on kk31 ----
    {
      const int q1 = 2*t + 1;
      if (q1 < 448){
        gcompute(1);
        if ((q1 & 31) == 31){ gstore((2 + q1/32)*16 + gbmi); gzero(); }
      }
    }

    __syncthreads();   // all waves' h (+xw epi) stores drained

    if (t < SQLEN-1 && tid == 0){
      __hip_atomic_store(fgrp + jg, (u32)(t+1), __ATOMIC_RELAXED,
                         __HIP_MEMORY_SCOPE_AGENT);   // plain store, no RMW
      if ((t & 15) == 15 && t < 224)
        __hip_atomic_fetch_add(gcnt + (2 + (t>>4))*16 + gbmi, 1u,
                               __ATOMIC_RELAXED, __HIP_MEMORY_SCOPE_AGENT);
    }
  }
}

// ---- phase 3: out[b][c] = h[b]. Wfc[c] + bfc[c], fp32. 256 blocks:
// 32 b-groups x 8 class-slices of 125. ----
__global__ __launch_bounds__(256) void fc_kernel(const short* __restrict__ h,
    const float* __restrict__ wfc, const float* __restrict__ bfc, float* __restrict__ out)
{
  __shared__ float hs[4][1024];
  int tid = threadIdx.x;
  int b0 = (blockIdx.x >> 3)*4;
  int cs = (blockIdx.x & 7)*125;
  for (int i = tid; i < 4096; i += 256){
    int bb = i >> 10, k = i & 1023;
    hs[bb][k] = bf2f(h[(size_t)(b0+bb)*HID + k]);
  }
  __syncthreads();
  for (int c = cs + tid; c < cs + 125; c += 256){
    const float* w = wfc + (size_t)c*HID;
    float a0=0.f,a1=0.f,a2=0.f,a3=0.f;
    for (int k=0; k<1024; k+=4){
      float4 wv = *(const float4*)(w + k);
      a0 += wv.x*hs[0][k] + wv.y*hs[0][k+1] + wv.z*hs[0][k+2] + wv.w*hs[0][k+3];
      a1 += wv.x*hs[1][k] + wv.y*hs[1][k+1] + wv.z*hs[1][k+2] + wv.w*hs[1][k+3];
      a2 += wv.x*hs[2][k] + wv.y*hs[2][k+1] + wv.z*hs[2][k+2] + wv.w*hs[2][k+3];
      a3 += wv.x*hs[3][k] + wv.y*hs[3][k+1] + wv.z*hs[3][k+2] + wv.w*hs[3][k+3];
    }
    float bb = bfc[c];
    out[(size_t)(b0+0)*NCLS + c] = a0 + bb;
    out[(size_t)(b0+1)*NCLS + c] = a1 + bb;
    out[(size_t)(b0+2)*NCLS + c] = a2 + bb;
    out[(size_t)(b0+3)*NCLS + c] = a3 + bb;
  }
}

extern "C" void kernel_launch(void* const* d_in, const int* in_sizes, int n_in,
                              void* d_out, int out_size, void* d_ws, size_t ws_size,
                              hipStream_t stream) {
  const float* x   = (const float*)d_in[0];
  const float* Wxh = (const float*)d_in[1];
  const float* bxh = (const float*)d_in[2];
  const float* Whh = (const float*)d_in[3];
  const float* bhh = (const float*)d_in[4];
  const float* Wfc = (const float*)d_in[5];
  const float* bfc = (const float*)d_in[6];
  float* out = (float*)d_out;

  char* ws = (char*)d_ws;
  // xbf stays LIVE through the fused kernel (gemm A source) -> h_all does
  // not alias it; workspace high-water ~422 MB.
  short*    xbf   = (short*)(ws + 0);            // 64 MB
  short*    wxhb  = (short*)(ws + 68157440);     // 65 MB
  short*    whhb  = (short*)(ws + 76546048);     // 73 MB
  float*    biasg = (float*)(ws + 84934656);     // 81 MB
  short*    xw    = (short*)(ws + 85983232);     // 82 MB, 256 MB gate-blocked
  short*    h_all = (short*)(ws + 354418688);    // 338 MB, 257 x 256 KB
  u32*      flags = (u32*)(ws + 421789696);      // 512 h-flags
  u32*      gcnt  = (u32*)(ws + 421793792);      // 256 per-s gemm counters

  hipMemsetAsync(flags, 0, 8192, stream);        // covers flags + gcnt

  cast_x_kernel<<<32768, 256, 0, stream>>>(x, xbf);
  cast_w_kernel<<<4096, 256, 0, stream>>>(Wxh, wxhb);
  cast_w_kernel<<<4096, 256, 0, stream>>>(Whh, whhb);
  bias_kernel  <<<16,   256, 0, stream>>>(bxh, bhh, biasg);
  hipMemsetAsync(h_all, 0, 262144, stream);      // h_all[0] = 0
  lstm_fused_kernel<<<512, 256, 0, stream>>>(xbf, wxhb, biasg, whhb,
                                             xw, h_all, flags, gcnt);
  fc_kernel    <<<256,  256, 0, stream>>>(h_all + (size_t)SQLEN*131072, Wfc, bfc, out);
}

// Round 9
// 1598.892 us; speedup vs baseline: 1.7198x; 1.7198x over previous
//
#include <hip/hip_runtime.h>
#include <hip/hip_bf16.h>

typedef __attribute__((ext_vector_type(8))) short short8;
typedef __attribute__((ext_vector_type(4))) float f32x4;
typedef unsigned long long u64;
typedef unsigned int u32;

#define SQLEN 256
#define BATCH 128
#define HID   1024
#define G4    4096
#define NCLS  1000

static __device__ __forceinline__ float sigm(float x){ return 1.0f/(1.0f+__expf(-x)); }
static __device__ __forceinline__ float tanhx(float x){ return 2.0f/(1.0f+__expf(-2.0f*x)) - 1.0f; }
static __device__ __forceinline__ short bf16b(float x){
  __hip_bfloat16 h = __float2bfloat16(x);
  return __builtin_bit_cast(short, h);
}
static __device__ __forceinline__ float bf2f(short s){
  return __bfloat162float(__builtin_bit_cast(__hip_bfloat16, s));
}

// ---- prep: cast x [B][S][I] fp32 -> xbf [(s*128+b)][I] bf16 (permuted) ----
__global__ void cast_x_kernel(const float* __restrict__ x, short* __restrict__ xbf){
  int r = blockIdx.x;            // r = s*128 + b
  int s = r >> 7, b = r & 127;
  const float* src = x + ((size_t)b*SQLEN + s)*HID;
  short* dst = xbf + (size_t)r*HID;
  int k = threadIdx.x*4;
  float4 v = *(const float4*)(src + k);
  short4 o; o.x=bf16b(v.x); o.y=bf16b(v.y); o.z=bf16b(v.z); o.w=bf16b(v.w);
  *(short4*)(dst + k) = o;
}

__global__ void cast_w_kernel(const float* __restrict__ src, short* __restrict__ dst){
  int i = (blockIdx.x*256 + threadIdx.x)*4;
  float4 v = *(const float4*)(src + i);
  short4 o; o.x=bf16b(v.x); o.y=bf16b(v.y); o.z=bf16b(v.z); o.w=bf16b(v.w);
  *(short4*)(dst + i) = o;
}

__global__ void bias_kernel(const float* __restrict__ a, const float* __restrict__ b,
                            float* __restrict__ o){
  int i = blockIdx.x*256 + threadIdx.x;
  o[i] = a[i] + b[i];
}

// ---- phase 1: xw GEMM (M=32768,N=4096,K=1024). global_load_lds staging.
// Output gate-blocked: xw[((s*64 + jg)*128 + b)*64 + g*16 + jj]
// ONE change vs R1: XCD-chunked bijective block swizzle (T1). Default
// bid=bm*32+bn round-robins XCDs, so the 32 bn-blocks sharing one 256KB
// A-panel land on all 8 XCDs -> A fetched into 8 L2s (~512MB HBM traffic
// instead of 64MB). swz=(bid&7)*1024+(bid>>3): consecutive dispatches on
// one XCD walk bn within a single bm -> A-panel is XCD-L2-resident.
// Bijective: 8192 = 8 x 1024.
__global__ __launch_bounds__(256,3) void gemm_xw_kernel(
    const short* __restrict__ A, const short* __restrict__ B,
    const float* __restrict__ bias, short* __restrict__ C)
{
  __shared__ __align__(16) short As[4096];   // [128][32]
  __shared__ __align__(16) short Bs[4096];
  const int tid = threadIdx.x;
  const int swz = (((int)blockIdx.x & 7) << 10) + ((int)blockIdx.x >> 3);
  const int bm = swz >> 5;            // 0..255  (= s index)
  const int bn = swz & 31;            // 0..31
  const size_t r0 = (size_t)bm*128, n0 = (size_t)bn*128;
  const int lane = tid & 63, wave = tid >> 6;
  const int wm = (wave>>1)*64, wn = (wave&1)*64;
  const int l15 = lane & 15, quad = lane >> 4;

  f32x4 acc[4][4];
  #pragma unroll
  for (int m=0;m<4;++m)
    #pragma unroll
    for (int n=0;n<4;++n) acc[m][n] = (f32x4)0.0f;

  const int c0 = wave*64 + lane;      // staging slot, rep 0
  const int c1 = c0 + 256;            // rep 1

  for (int kk = 0; kk < 32; ++kk){
    const int k0 = kk*32;
    __syncthreads();   // previous iter's LDS reads done
    // async DMA global -> LDS, 16B per lane, lane-contiguous dest
    __builtin_amdgcn_global_load_lds(
        (const void*)(A + (r0 + (c0>>2))*HID + k0 + (c0&3)*8),
        (void*)((char*)As + wave*1024), 16, 0, 0);
    __builtin_amdgcn_global_load_lds(
        (const void*)(A + (r0 + (c1>>2))*HID + k0 + (c1&3)*8),
        (void*)((char*)As + 4096 + wave*1024), 16, 0, 0);
    __builtin_amdgcn_global_load_lds(
        (const void*)(B + (n0 + (c0>>2))*HID + k0 + (c0&3)*8),
        (void*)((char*)Bs + wave*1024), 16, 0, 0);
    __builtin_amdgcn_global_load_lds(
        (const void*)(B + (n0 + (c1>>2))*HID + k0 + (c1&3)*8),
        (void*)((char*)Bs + 4096 + wave*1024), 16, 0, 0);
    __syncthreads();   // DMA landed (barrier drains vmcnt)
    short8 af[4], bf[4];
    #pragma unroll
    for (int m=0;m<4;++m) af[m] = *(const short8*)(As + (wm + m*16 + l15)*32 + quad*8);
    #pragma unroll
    for (int n=0;n<4;++n) bf[n] = *(const short8*)(Bs + (wn + n*16 + l15)*32 + quad*8);
    #pragma unroll
    for (int m=0;m<4;++m)
      #pragma unroll
      for (int n=0;n<4;++n)
        acc[m][n] = __builtin_amdgcn_mfma_f32_16x16x32_bf16(af[m], bf[n], acc[m][n], 0,0,0);
  }
  // epilogue: pack 4 adjacent bf16 -> 8B stores
  #pragma unroll
  for (int n=0;n<4;++n){
    int s = (int)n0 + wn + n*16;          // start col, multiple of 16
    float bs = bias[s + l15];
    int g = s >> 10, jgi = (s & 1023) >> 4;
    #pragma unroll
    for (int m=0;m<4;++m){
      #pragma unroll
      for (int rg=0; rg<4; ++rg){
        u32 w0 = (u32)(unsigned short)bf16b(acc[m][n][rg] + bs);
        u32 w1 = __shfl_down(w0, 1);
        u32 w2 = __shfl_down(w0, 2);
        u32 w3 = __shfl_down(w0, 3);
        if ((l15 & 3) == 0){
          u64 pk = (u64)w0 | ((u64)w1<<16) | ((u64)w2<<32) | ((u64)w3<<48);
          int rowin = wm + m*16 + quad*4 + rg;    // batch b 0..127
          *(u64*)(C + (((size_t)bm*64 + jgi)*128 + rowin)*64 + g*16 + l15) = pk;
        }
      }
    }
  }
}

// ---- phase 2: persistent LSTM recurrence -- BYTE-EXACT R1 (962us).
// Every modification attempted (AGPR/VGPR pinning, per-wave release
// protocol, 3 fusion variants) regressed; this structure is banked. ----
__global__ __launch_bounds__(256,2) void lstm_kernel(
    const short* __restrict__ whh, const short* __restrict__ xw,
    short* __restrict__ h_all, u32* __restrict__ flags)
{
  __shared__ f32x4 part[2][4][4][64];   // [buf][wave][gate][lane] = 32 KB

  const int tid  = threadIdx.x;
  const int lane = tid & 63;
  const int wave = tid >> 6;            // K-slice 0..3 (256 each)
  const int l15  = lane & 15;
  const int quad = lane >> 4;
  const int bg = blockIdx.x & 7;        // batch group
  const int jg = blockIdx.x >> 3;       // 0..63
  const int b0 = bg*16;
  const int j0 = jg*16;
  const int ks0 = wave*256;

  __builtin_amdgcn_fence(__ATOMIC_ACQUIRE, "agent");  // once: clear stale L2

  // Whh slice, MFMA B-fragment layout (no pinning -- rounds 2/3)
  short8 Bf[4][8];
  #pragma unroll
  for (int g=0; g<4; ++g)
    #pragma unroll
    for (int kit=0; kit<8; ++kit)
      Bf[g][kit] = *(const short8*)(whh + (size_t)(g*1024 + j0 + l15)*HID
                                    + ks0 + kit*32 + quad*8);

  u32* fgrp = flags + bg*64;            // one flag per producer block

  // elementwise cell mapping: cell = tid (r 0..15 x jj 0..15)
  const int r  = tid >> 4;
  const int jj = tid & 15;
  const int ln = (r>>2)*16 + jj;        // frag lane of cell
  const int rg = r & 3;                 // frag reg of cell
  float cc = 0.0f;                      // cell state in register

  // prefetch xw for t=0
  short xwc[4];
  {
    const short* xb = xw + (((size_t)0*64 + jg)*128 + b0 + r)*64 + jj;
    #pragma unroll
    for (int g=0; g<4; ++g) xwc[g] = xb[g*16];
  }

  for (int t = 0; t < SQLEN; ++t){
    const short* hin  = h_all + (size_t)t*131072;
    short*       hout = h_all + (size_t)(t+1)*131072;

    // prefetch next step's xw early (independent of h)
    short xwn[4];
    if (t < SQLEN-1){
      const short* xb = xw + (((size_t)(t+1)*64 + jg)*128 + b0 + r)*64 + jj;
      #pragma unroll
      for (int g=0; g<4; ++g) xwn[g] = xb[g*16];
    }

    // per-wave spin: only the 16 producer blocks of THIS wave's K-slice.
    if (t){
      u32* fp = fgrp + wave*16 + l15;
      while (__hip_atomic_load(fp, __ATOMIC_RELAXED,
                               __HIP_MEMORY_SCOPE_AGENT) < (u32)t)
        __builtin_amdgcn_s_sleep(1);
      asm volatile("" ::: "memory");    // no hoist of h loads above the spin
    }

    // h fragments: plain cached coalesced 16B loads (fresh addresses)
    short8 Af[8];
    #pragma unroll
    for (int kit=0; kit<8; ++kit)
      Af[kit] = *(const short8*)(hin + (size_t)(b0 + l15)*HID
                                 + ks0 + kit*32 + quad*8);

    f32x4 acc[4];
    #pragma unroll
    for (int g=0; g<4; ++g) acc[g] = (f32x4)0.0f;
    #pragma unroll
    for (int kit=0; kit<8; ++kit)
      #pragma unroll
      for (int g=0; g<4; ++g)
        acc[g] = __builtin_amdgcn_mfma_f32_16x16x32_bf16(Af[kit], Bf[g][kit], acc[g],0,0,0);

    // single-pass cross-wave reduce, all 4 gates, double-buffered
    const int pb = t & 1;
    #pragma unroll
    for (int g=0; g<4; ++g) part[pb][wave][g][lane] = acc[g];
    __syncthreads();

    float gv[4];
    #pragma unroll
    for (int g=0; g<4; ++g){
      float s = bf2f(xwc[g]);
      #pragma unroll
      for (int w=0; w<4; ++w)
        s += ((const float*)&part[pb][w][g][ln])[rg];
      gv[g] = s;
    }

    float it = sigm(gv[0]), ft = sigm(gv[1]), ch = tanhx(gv[2]), ot = sigm(gv[3]);
    cc = cc*ft + it*ch;
    float hv = ot * tanhx(cc);

    // pack 4 adjacent cells -> one 8B write-through store
    u32 w0 = (u32)(unsigned short)bf16b(hv);
    u32 w1 = __shfl_down(w0, 1);
    u32 w2 = __shfl_down(w0, 2);
    u32 w3 = __shfl_down(w0, 3);
    if (!(tid & 3)){
      u64 hp = (u64)w0 | ((u64)w1<<16) | ((u64)w2<<32) | ((u64)w3<<48);
      __hip_atomic_store((u64*)(hout + (size_t)(b0 + r)*HID + j0 + jj), hp,
                         __ATOMIC_RELAXED, __HIP_MEMORY_SCOPE_AGENT);
    }
    xwc[0]=xwn[0]; xwc[1]=xwn[1]; xwc[2]=xwn[2]; xwc[3]=xwn[3];
    __syncthreads();   // all waves' h stores drained (vmcnt0 at barrier)

    if (t < SQLEN-1 && tid == 0)
      __hip_atomic_store(fgrp + jg, (u32)(t+1), __ATOMIC_RELAXED,
                         __HIP_MEMORY_SCOPE_AGENT);   // plain store, no RMW
  }
}

// ---- phase 3: out[b][c] = h[b]. Wfc[c] + bfc[c], fp32. 256 blocks:
// 32 b-groups x 8 class-slices of 125 (proven in rounds 6-8). ----
__global__ __launch_bounds__(256) void fc_kernel(const short* __restrict__ h,
    const float* __restrict__ wfc, const float* __restrict__ bfc, float* __restrict__ out)
{
  __shared__ float hs[4][1024];
  int tid = threadIdx.x;
  int b0 = (blockIdx.x >> 3)*4;
  int cs = (blockIdx.x & 7)*125;
  for (int i = tid; i < 4096; i += 256){
    int bb = i >> 10, k = i & 1023;
    hs[bb][k] = bf2f(h[(size_t)(b0+bb)*HID + k]);
  }
  __syncthreads();
  for (int c = cs + tid; c < cs + 125; c += 256){
    const float* w = wfc + (size_t)c*HID;
    float a0=0.f,a1=0.f,a2=0.f,a3=0.f;
    for (int k=0; k<1024; k+=4){
      float4 wv = *(const float4*)(w + k);
      a0 += wv.x*hs[0][k] + wv.y*hs[0][k+1] + wv.z*hs[0][k+2] + wv.w*hs[0][k+3];
      a1 += wv.x*hs[1][k] + wv.y*hs[1][k+1] + wv.z*hs[1][k+2] + wv.w*hs[1][k+3];
      a2 += wv.x*hs[2][k] + wv.y*hs[2][k+1] + wv.z*hs[2][k+2] + wv.w*hs[2][k+3];
      a3 += wv.x*hs[3][k] + wv.y*hs[3][k+1] + wv.z*hs[3][k+2] + wv.w*hs[3][k+3];
    }
    float bb = bfc[c];
    out[(size_t)(b0+0)*NCLS + c] = a0 + bb;
    out[(size_t)(b0+1)*NCLS + c] = a1 + bb;
    out[(size_t)(b0+2)*NCLS + c] = a2 + bb;
    out[(size_t)(b0+3)*NCLS + c] = a3 + bb;
  }
}

extern "C" void kernel_launch(void* const* d_in, const int* in_sizes, int n_in,
                              void* d_out, int out_size, void* d_ws, size_t ws_size,
                              hipStream_t stream) {
  const float* x   = (const float*)d_in[0];
  const float* Wxh = (const float*)d_in[1];
  const float* bxh = (const float*)d_in[2];
  const float* Whh = (const float*)d_in[3];
  const float* bhh = (const float*)d_in[4];
  const float* Wfc = (const float*)d_in[5];
  const float* bfc = (const float*)d_in[6];
  float* out = (float*)d_out;

  char* ws = (char*)d_ws;
  // h_all (257 x 256KB = 64.25MB) ALIASES xbf (64MB): xbf dead after gemm.
  short*    h_all = (short*)(ws + 0);
  short*    xbf   = (short*)(ws + 0);
  short*    wxhb  = (short*)(ws + 68157440);     // 65 MB
  short*    whhb  = (short*)(ws + 76546048);     // 73 MB
  float*    biasg = (float*)(ws + 84934656);     // 81 MB
  short*    xw    = (short*)(ws + 85983232);     // 82 MB, 256 MB gate-blocked
  u32*      flags = (u32*)(ws + 354418688);      // 512 producer flags

  hipMemsetAsync(flags, 0, 4096, stream);

  cast_x_kernel<<<32768, 256, 0, stream>>>(x, xbf);
  cast_w_kernel<<<4096, 256, 0, stream>>>(Wxh, wxhb);
  cast_w_kernel<<<4096, 256, 0, stream>>>(Whh, whhb);
  bias_kernel  <<<16,   256, 0, stream>>>(bxh, bhh, biasg);
  gemm_xw_kernel<<<8192, 256, 0, stream>>>(xbf, wxhb, biasg, xw);
  // xbf now dead; zero h_all[0] (t=0 input state)
  hipMemsetAsync(ws, 0, 262144, stream);
  lstm_kernel  <<<512,  256, 0, stream>>>(whhb, xw, h_all, flags);
  fc_kernel    <<<256,  256, 0, stream>>>(h_all + (size_t)SQLEN*131072, Wfc, bfc, out);
}